// Round 16
// baseline (143.302 us; speedup 1.0000x reference)
//
#include <hip/hip_runtime.h>

typedef float f32x4 __attribute__((ext_vector_type(4)));

#define NB 16
#define NC 64
#define NH 128
#define NW 128
#define STRIPE 8
#define LROWS 10      // 8 output rows + 2 halo rows
#define LCOLS 72      // 18 col-groups of 4: input q = w0 .. w0+71

// One dispatch, 512 blocks = (batch 16) x (row-stripe 16) x (col-half 2), 256 threads.
//   threads 0..179 : X  - channel-sum one (row, colgroup4) into LDS (64 f32x4 loads, 8 chains)
//   threads 180..255: W  - flipped channel-summed weights + bias (concurrent, L2-hot)
//   after 1 barrier : C  - each thread: 32 couts x 4 cols from registers
__global__ __launch_bounds__(256, 4) void fused_conv_kernel(
    const float* __restrict__ x, const float* __restrict__ wgt,
    const float* __restrict__ bias, float* __restrict__ out) {
  __shared__ float xs[LROWS][LCOLS];   // channel-summed window
  __shared__ float wl[64][12];         // [o][0..8]=flipped wsum, [9]=bias

  const int t   = threadIdx.x;
  const int bid = blockIdx.x;
  const int b   = bid >> 5;
  const int r5  = bid & 31;
  const int R0  = (r5 >> 1) * STRIPE;  // output row base
  const int h   = r5 & 1;
  const int ch0 = h * 64;              // output col base
  const int w0  = ch0 - 4;             // input q of xs col 0

  if (t < 180) {
    // ---- X: xs[row][4g..4g+3] = sum_c x[b,c,R0-1+row, w0+4g ..+3]
    const int row = t / 18;
    const int g   = t - row * 18;
    const int ir  = R0 - 1 + row;
    const int q0  = w0 + g * 4;
    f32x4 s0 = {0,0,0,0}, s1 = {0,0,0,0}, s2 = {0,0,0,0}, s3 = {0,0,0,0};
    f32x4 s4 = {0,0,0,0}, s5 = {0,0,0,0}, s6 = {0,0,0,0}, s7 = {0,0,0,0};
    if (ir >= 0 && ir < NH && q0 >= 0 && q0 <= NW - 4) {
      const float* xp = x + (b * NC * NH + ir) * NW + q0;
      #pragma unroll
      for (int c = 0; c < NC; c += 8) {
        s0 += *(const f32x4*)(xp + (c + 0) * (NH * NW));
        s1 += *(const f32x4*)(xp + (c + 1) * (NH * NW));
        s2 += *(const f32x4*)(xp + (c + 2) * (NH * NW));
        s3 += *(const f32x4*)(xp + (c + 3) * (NH * NW));
        s4 += *(const f32x4*)(xp + (c + 4) * (NH * NW));
        s5 += *(const f32x4*)(xp + (c + 5) * (NH * NW));
        s6 += *(const f32x4*)(xp + (c + 6) * (NH * NW));
        s7 += *(const f32x4*)(xp + (c + 7) * (NH * NW));
      }
    }
    *(f32x4*)&xs[row][g * 4] = ((s0 + s1) + (s2 + s3)) + ((s4 + s5) + (s6 + s7));
  } else {
    // ---- W: each (o,tap) owned by one thread; store flipped; then bias
    for (int s = t - 180; s < 640; s += 76) {
      if (s < 576) {
        const int o  = s / 9;
        const int t9 = s - o * 9;
        const float* wp = wgt + o * (NC * 9) + t9;
        float acc = 0.f;
        #pragma unroll 8
        for (int i = 0; i < NC; ++i) acc += wp[i * 9];
        wl[o][8 - t9] = acc;           // flipped tap position
      } else {
        wl[s - 576][9] = bias[s - 576];
      }
    }
  }
  __syncthreads();

  // ---- C: thread = (cout-half oh, row ro, colgroup g); 32 couts x 4 cols
  {
    const int oh = t >> 7;
    const int sp = t & 127;
    const int ro = sp >> 4;            // 0..7
    const int g  = sp & 15;            // col group within the 64-col half
    float X0[6], X1[6], X2[6];
    #pragma unroll
    for (int m = 0; m < 6; ++m) {
      X0[m] = xs[ro][4 * g + 3 + m];
      X1[m] = xs[ro + 1][4 * g + 3 + m];
      X2[m] = xs[ro + 2][4 * g + 3 + m];
    }
    float* op = out + ((b * 64 + oh * 32) * NH + R0 + ro) * NW + ch0 + 4 * g;
    for (int oi = 0; oi < 32; ++oi) {
      const int o = oh * 32 + oi;
      f32x4 wa = *(const f32x4*)&wl[o][0];   // wf0..wf3
      f32x4 wb = *(const f32x4*)&wl[o][4];   // wf4..wf7
      f32x4 wc = *(const f32x4*)&wl[o][8];   // wf8, bias, pad, pad
      f32x4 y;
      #pragma unroll
      for (int jj = 0; jj < 4; ++jj) {
        float acc = wc[1];
        acc += wa[0] * X0[jj] + wa[1] * X0[jj + 1] + wa[2] * X0[jj + 2];
        acc += wa[3] * X1[jj] + wb[0] * X1[jj + 1] + wb[1] * X1[jj + 2];
        acc += wb[2] * X2[jj] + wb[3] * X2[jj + 1] + wc[0] * X2[jj + 2];
        y[jj] = acc;
      }
      *(f32x4*)(op + oi * (NH * NW)) = y;
    }
  }
}

extern "C" void kernel_launch(void* const* d_in, const int* in_sizes, int n_in,
                              void* d_out, int out_size, void* d_ws, size_t ws_size,
                              hipStream_t stream) {
  const float* x    = (const float*)d_in[0];
  const float* wgt  = (const float*)d_in[1];
  const float* bias = (const float*)d_in[2];
  float* out = (float*)d_out;
  (void)in_sizes; (void)n_in; (void)out_size; (void)d_ws; (void)ws_size;

  // One dispatch: 16 batches x 16 row-stripes x 2 col-halves, 256 threads
  fused_conv_kernel<<<dim3(NB * 16 * 2), dim3(256), 0, stream>>>(x, wgt, bias, out);
}